// Round 22
// baseline (187.799 us; speedup 1.0000x reference)
//
#include <hip/hip_runtime.h>
#include <math.h>

#define BN 32
#define HN 512
#define WN 512
#define REGION 30
#define RPAD 32
#define UFV 20.0f
#define DFTSHIFT 15.0f
#define TWO_PI 6.2831853071795864769f
#define HS 8              // h-chunks for upsample_T partials
#define HCH (HN / HS)     // 64
#define WS 8              // w-chunks for upsample_U partials (32 w each)
#define WCH 32

typedef float2 cplx;

__device__ __forceinline__ cplx cmul(cplx a, cplx b){
    return make_float2(a.x*b.x - a.y*b.y, a.x*b.y + a.y*b.x);
}
__device__ __forceinline__ cplx cadd(cplx a, cplx b){
    return make_float2(a.x + b.x, a.y + b.y);
}
__device__ __forceinline__ cplx csub(cplx a, cplx b){
    return make_float2(a.x - b.x, a.y - b.y);
}
__device__ __forceinline__ int brev9(int i){ return (int)(__brev((unsigned)i) >> 23); }
__device__ __forceinline__ int brev6(int i){ return (int)(__brev((unsigned)i) >> 26); }
// col-FFT LDS layout: stride 546 (== 2 mod 16) + h>>4 skew -> ~4 lanes/bank-pair
__device__ __forceinline__ int csl(int h, int c){ return c * 546 + h + (h >> 4); }

#define BFLY(a,b,w){ cplx t_ = cmul(w,b); b = make_float2(a.x - t_.x, a.y - t_.y); a = cadd(a, t_); }
#define BFLY1(a,b){ cplx t_ = b; b = make_float2(a.x - t_.x, a.y - t_.y); a = cadd(a, t_); }

// ---- wave-level 512-pt FFT: 64 lanes, 8 elems/lane in registers, radix-2 DIT
// Input:  v[j] = x[brev9(8*lane+j)]   Output: v[j] = X[64*j + lane]
__device__ __forceinline__ void fft512_regs(cplx* v, const float2* tw, cplx* ds, int lane){
    const cplx wI  = *(const cplx*)&tw[128];   // (0, sign)
    const cplx w8a = *(const cplx*)&tw[64];
    const cplx w8b = *(const cplx*)&tw[192];
    BFLY1(v[0],v[1]); BFLY1(v[2],v[3]); BFLY1(v[4],v[5]); BFLY1(v[6],v[7]);
    BFLY1(v[0],v[2]); BFLY(v[1],v[3],wI); BFLY1(v[4],v[6]); BFLY(v[5],v[7],wI);
    BFLY1(v[0],v[4]); BFLY(v[1],v[5],w8a); BFLY(v[2],v[6],wI); BFLY(v[3],v[7],w8b);
    const int h = lane >> 3, lo = lane & 7;
    const int bw = 9 * lane;
    const int br = 72 * h + lo;
    #pragma unroll
    for (int j = 0; j < 8; ++j) ds[bw + j] = v[j];
    asm volatile("s_waitcnt lgkmcnt(0)" ::: "memory");
    #pragma unroll
    for (int j = 0; j < 8; ++j) v[j] = ds[br + 9*j];
    {
        cplx wA = *(const cplx*)&tw[lo<<5];
        BFLY(v[0],v[1],wA); BFLY(v[2],v[3],wA); BFLY(v[4],v[5],wA); BFLY(v[6],v[7],wA);
        cplx wB0 = *(const cplx*)&tw[lo<<4], wB1 = *(const cplx*)&tw[128+(lo<<4)];
        BFLY(v[0],v[2],wB0); BFLY(v[1],v[3],wB1); BFLY(v[4],v[6],wB0); BFLY(v[5],v[7],wB1);
        cplx wC0 = *(const cplx*)&tw[lo<<3], wC1 = *(const cplx*)&tw[64+(lo<<3)];
        cplx wC2 = *(const cplx*)&tw[128+(lo<<3)], wC3 = *(const cplx*)&tw[192+(lo<<3)];
        BFLY(v[0],v[4],wC0); BFLY(v[1],v[5],wC1); BFLY(v[2],v[6],wC2); BFLY(v[3],v[7],wC3);
    }
    #pragma unroll
    for (int j = 0; j < 8; ++j) ds[br + 9*j] = v[j];
    asm volatile("s_waitcnt lgkmcnt(0)" ::: "memory");
    const int br3 = lane + (lane >> 3);
    #pragma unroll
    for (int j = 0; j < 8; ++j) v[j] = ds[br3 + 72*j];
    {
        cplx wD = *(const cplx*)&tw[lane<<2];
        BFLY(v[0],v[1],wD); BFLY(v[2],v[3],wD); BFLY(v[4],v[5],wD); BFLY(v[6],v[7],wD);
        cplx wE0 = *(const cplx*)&tw[lane<<1], wE1 = *(const cplx*)&tw[128+(lane<<1)];
        BFLY(v[0],v[2],wE0); BFLY(v[1],v[3],wE1); BFLY(v[4],v[6],wE0); BFLY(v[5],v[7],wE1);
        cplx wF0 = *(const cplx*)&tw[lane], wF1 = *(const cplx*)&tw[64+lane];
        cplx wF2 = *(const cplx*)&tw[128+lane], wF3 = *(const cplx*)&tw[192+lane];
        BFLY(v[0],v[4],wF0); BFLY(v[1],v[5],wF1); BFLY(v[2],v[6],wF2); BFLY(v[3],v[7],wF3);
    }
}

// Packed row FFT: F_z rows of z = tgt + i*src. Wave-per-row. grid (BN*HN/4), block 256.
__global__ void __launch_bounds__(256) row_fft_pack(const float* __restrict__ tgt,
                                                    const float* __restrict__ src,
                                                    cplx* __restrict__ Fz){
    __shared__ float2 tw[256];
    __shared__ cplx ds[4 * 576];
    const int tid = threadIdx.x;
    { float sv, cv; sincosf(-TWO_PI * (float)tid * (1.0f/512.0f), &sv, &cv);
      tw[tid] = make_float2(cv, sv); }
    __syncthreads();
    const int wave = tid >> 6, lane = tid & 63;
    const int rid = blockIdx.x * 4 + wave;
    const float* tr = tgt + (size_t)rid * WN;
    const float* sr = src + (size_t)rid * WN;
    const int rb6 = brev6(lane);
    const int B3[8] = {0,256,128,384,64,320,192,448};      // brev3(j)*64
    cplx v[8];
    #pragma unroll
    for (int j = 0; j < 8; ++j){ int o = B3[j] + rb6; v[j] = make_float2(tr[o], sr[o]); }
    fft512_regs(v, (const float2*)tw, ds + wave * 576, lane);
    cplx* orow = Fz + (size_t)rid * WN;
    #pragma unroll
    for (int j = 0; j < 8; ++j) orow[64*j + lane] = v[j];
}

// ---- radix-8 column FFT, 8 cols/block, 512 threads: one radix-8 group per
// thread per pass, data staged BIT-REVERSED so pass 0 is in-place.
__device__ __forceinline__ void col_fft8_t512(cplx* sm, const float2* tw, int tid){
    const cplx wI  = tw[128];
    const cplx w8a = tw[64];
    const cplx w8b = tw[192];
    const int c = tid & 7;
    const int k = tid >> 3;                 // 0..63
    {
        cplx y[8];
        #pragma unroll
        for (int m = 0; m < 8; ++m) y[m] = sm[csl(8*k + m, c)];
        BFLY1(y[0],y[1]); BFLY1(y[2],y[3]); BFLY1(y[4],y[5]); BFLY1(y[6],y[7]);
        BFLY1(y[0],y[2]); BFLY(y[1],y[3],wI); BFLY1(y[4],y[6]); BFLY(y[5],y[7],wI);
        BFLY1(y[0],y[4]); BFLY(y[1],y[5],w8a); BFLY(y[2],y[6],wI); BFLY(y[3],y[7],w8b);
        #pragma unroll
        for (int m = 0; m < 8; ++m) sm[csl(8*k + m, c)] = y[m];
    }
    __syncthreads();
    #pragma unroll
    for (int pass = 1; pass < 3; ++pass){
        const int st = 3*pass + 1;          // 4, 7
        const int h1 = 1 << (st - 1);       // 8, 64
        const int q = k & (h1 - 1);
        const int i0 = ((k >> (st - 1)) << (st + 2)) + q;
        cplx x[8];
        #pragma unroll
        for (int m = 0; m < 8; ++m) x[m] = sm[csl(i0 + m*h1, c)];
        cplx w1 = tw[q << (9 - st)];
        BFLY(x[0],x[1],w1); BFLY(x[2],x[3],w1); BFLY(x[4],x[5],w1); BFLY(x[6],x[7],w1);
        cplx w2a = tw[q << (8 - st)];
        cplx w2b = tw[(q << (8 - st)) + 128];
        BFLY(x[0],x[2],w2a); BFLY(x[1],x[3],w2b); BFLY(x[4],x[6],w2a); BFLY(x[5],x[7],w2b);
        cplx w30 = tw[q << (7 - st)];
        cplx w31 = tw[(q << (7 - st)) + 64];
        cplx w32 = tw[(q << (7 - st)) + 128];
        cplx w33 = tw[(q << (7 - st)) + 192];
        BFLY(x[0],x[4],w30); BFLY(x[1],x[5],w31); BFLY(x[2],x[6],w32); BFLY(x[3],x[7],w33);
        #pragma unroll
        for (int m = 0; m < 8; ++m) sm[csl(i0 + m*h1, c)] = x[m];
        __syncthreads();
    }
}

// Column-wise forward FFT of F_z, 8 cols/block, 512 threads, in place. grid (WN/8, BN).
__global__ void __launch_bounds__(512) col_fft_fwd(cplx* __restrict__ buf){
    const int b  = blockIdx.y;
    const int w0 = blockIdx.x * 8;
    const int tid = threadIdx.x;
    __shared__ cplx sm[4368];
    __shared__ float2 tw[256];
    if (tid < 256){ float sv, cv; sincosf(-TWO_PI * (float)tid * (1.0f/512.0f), &sv, &cv);
      tw[tid] = make_float2(cv, sv); }
    cplx* base = buf + (size_t)b * HN * WN + w0;
    for (int idx = tid; idx < HN * 4; idx += 512){
        int h = idx >> 2, c2 = (idx & 3) << 1;
        float4 v = *(const float4*)(base + (size_t)h * WN + c2);
        int hb = brev9(h);
        sm[csl(hb, c2)]     = make_float2(v.x, v.y);
        sm[csl(hb, c2 + 1)] = make_float2(v.z, v.w);
    }
    __syncthreads();
    col_fft8_t512(sm, (const float2*)tw, tid);
    for (int idx = tid; idx < HN * 4; idx += 512){
        int h = idx >> 2, c2 = (idx & 3) << 1;
        cplx a = sm[csl(h, c2)], d = sm[csl(h, c2 + 1)];
        *(float4*)(base + (size_t)h * WN + c2) = make_float4(a.x, a.y, d.x, d.y);
    }
}

// Hermitian unpack + cross-power + row-wise inverse FFT. Wave-per-row-pair.
// Mirror cc rows NOT written (colinv reconstructs, bit-exact). P written only
// for w < 320 (downstream reads are all w<=256). grid (65, BN), block 256.
__global__ void __launch_bounds__(256) cross_rowinv(cplx* __restrict__ Fz, cplx* __restrict__ cc){
    __shared__ float2 tw[256];
    __shared__ cplx ds[4 * 1184];
    const int tid = threadIdx.x;
    { float sv, cv; sincosf(TWO_PI * (float)tid * (1.0f/512.0f), &sv, &cv);
      tw[tid] = make_float2(cv, sv); }
    __syncthreads();
    const int wave = tid >> 6, lane = tid & 63;
    const int p = blockIdx.x * 4 + wave;
    if (p > 256) return;
    const int b = blockIdx.y;
    const int h1 = p, h2 = (HN - p) & (HN - 1);
    cplx* r1 = Fz + ((size_t)b * HN + h1) * WN;
    cplx* r2 = Fz + ((size_t)b * HN + h2) * WN;
    cplx* A = ds + wave * 1184;
    cplx* B = A + 592;
    #pragma unroll
    for (int u = 0; u < 8; ++u){
        A[lane + 64*u] = r1[lane + 64*u];
        B[lane + 64*u] = r2[lane + 64*u];
    }
    asm volatile("s_waitcnt lgkmcnt(0)" ::: "memory");
    const int rb6 = brev6(lane);
    const int B3[8] = {0,256,128,384,64,320,192,448};
    cplx v1[8];
    #pragma unroll
    for (int j = 0; j < 8; ++j){
        int w  = B3[j] + rb6;
        int wm = (WN - w) & (WN - 1);
        cplx Aw = A[w], Bw = B[w], Am = A[wm], Bm = B[wm];
        // P(k) = -i*(X - conj(Y))*conj(X + conj(Y))/4
        { cplx Bc = make_float2(Bm.x, -Bm.y);
          cplx s = cadd(Aw, Bc);
          cplx d = make_float2(Aw.x - Bc.x, Aw.y - Bc.y);
          cplx D = make_float2(d.x*s.x + d.y*s.y, d.y*s.x - d.x*s.y);
          v1[j] = make_float2(0.25f * D.y, -0.25f * D.x); }
        if (w < 320){
          cplx Ac = make_float2(Am.x, -Am.y);
          cplx s = cadd(Bw, Ac);
          cplx d = make_float2(Bw.x - Ac.x, Bw.y - Ac.y);
          cplx D = make_float2(d.x*s.x + d.y*s.y, d.y*s.x - d.x*s.y);
          r2[w] = make_float2(0.25f * D.y, -0.25f * D.x);     // P row h2 writeback
          r1[w] = v1[j];                                      // P row h1 writeback
        }
    }
    fft512_regs(v1, (const float2*)tw, A, lane);
    cplx* c1 = cc + ((size_t)b * HN + h1) * WN;
    #pragma unroll
    for (int j = 0; j < 8; ++j) c1[64*j + lane] = v1[j];
    // mirror rows 257..511 intentionally not written (reconstructed in colinv)
}

// Column-wise inverse FFT + per-block argmax of |cc|^2. 512 threads. grid (WN/8, BN).
__global__ void __launch_bounds__(512) colinv_argmax(const cplx* __restrict__ buf,
                                                     float2* __restrict__ cand){
    const int b  = blockIdx.y;
    const int w0 = blockIdx.x * 8;
    const int tid = threadIdx.x;
    __shared__ cplx sm[4368];
    __shared__ float2 tw[256];
    __shared__ float wv_[8];
    __shared__ int   wi_[8];
    if (tid < 256){ float sv, cv; sincosf(TWO_PI * (float)tid * (1.0f/512.0f), &sv, &cv);
      tw[tid] = make_float2(cv, sv); }
    const cplx* base = buf + (size_t)b * HN * WN + w0;
    for (int idx = tid; idx < 257 * 4; idx += 512){
        int h = idx >> 2, c2 = (idx & 3) << 1;
        float4 v = *(const float4*)(base + (size_t)h * WN + c2);
        int hb = brev9(h);
        sm[csl(hb, c2)]     = make_float2(v.x, v.y);
        sm[csl(hb, c2 + 1)] = make_float2(v.z, v.w);
    }
    __syncthreads();
    for (int idx = tid; idx < 255 * 8; idx += 512){
        int h = 257 + (idx >> 3), c = idx & 7;
        cplx v = sm[csl(brev9(HN - h), c)];
        sm[csl(brev9(h), c)] = make_float2(v.x, -v.y);
    }
    __syncthreads();
    col_fft8_t512(sm, (const float2*)tw, tid);
    float best = -1.0f; int bidx = 0x7fffffff;
    for (int idx = tid; idx < HN * 8; idx += 512){
        int h = idx >> 3, c = idx & 7;
        cplx v = sm[csl(h, c)];
        float mm = v.x * v.x + v.y * v.y;
        if (mm > best){ best = mm; bidx = h * WN + w0 + c; }
    }
    for (int off = 32; off > 0; off >>= 1){
        float v2 = __shfl_down(best, off);
        int   i2 = __shfl_down(bidx, off);
        if (v2 > best || (v2 == best && i2 < bidx)){ best = v2; bidx = i2; }
    }
    if ((tid & 63) == 0){ wv_[tid >> 6] = best; wi_[tid >> 6] = bidx; }
    __syncthreads();
    if (tid == 0){
        float bv = wv_[0]; int bx = wi_[0];
        #pragma unroll
        for (int w2 = 1; w2 < 8; ++w2){
            if (wv_[w2] > bv || (wv_[w2] == bv && wi_[w2] < bx)){ bv = wv_[w2]; bx = wi_[w2]; }
        }
        cand[b * 64 + blockIdx.x] = make_float2(bv, __int_as_float(bx));
    }
}

// Reduce 64 candidates per batch -> coarse shifts + upsample offsets. grid BN, block 64.
__global__ void coarse_reduce(const float2* __restrict__ cand, float* __restrict__ small){
    const int b = blockIdx.x, t = threadIdx.x;
    float2 c = cand[b * 64 + t];
    float v = c.x; int ix = __float_as_int(c.y);
    for (int off = 32; off > 0; off >>= 1){
        float v2 = __shfl_down(v, off);
        int   i2 = __shfl_down(ix, off);
        if (v2 > v || (v2 == v && i2 < ix)){ v = v2; ix = i2; }
    }
    if (t == 0){
        int row = ix / WN, col = ix % WN;
        float sr = (row > HN / 2) ? (float)(row - HN) : (float)row;
        float sc = (col > WN / 2) ? (float)(col - WN) : (float)col;
        small[b * 4 + 0] = sr;
        small[b * 4 + 1] = sc;
        small[b * 4 + 2] = DFTSHIFT - sr * UFV;
        small[b * 4 + 3] = DFTSHIFT - sc * UFV;
    }
}

// Partial T for w = 0..255 (w=256 via upsample_T256; w>256 via Hermitian fold).
// grid (4, BN, HS=8), block 256 = 8 r-groups x 32 w-pairs.
// rk table TRANSPOSED [HCH][RPAD]: per-row reads are 2 x b128 (contiguous r).
__global__ void __launch_bounds__(256, 3) upsample_T(const cplx* __restrict__ P,
                                                     const float* __restrict__ small,
                                                     cplx* __restrict__ Tpart){
    const int b = blockIdx.y, hs = blockIdx.z;
    const int tid = threadIdx.x;
    const int wp = tid & 31;
    const int rbase = tid >> 5;
    const int w = blockIdx.x * 64 + wp * 2;
    const int h0 = hs * HCH;
    const float off0 = small[b * 4 + 2];
    const float CC = TWO_PI / (HN * UFV);
    __shared__ float2 rkT[HCH][RPAD];     // 16 KB, transposed
    for (int idx = tid; idx < HCH * RPAD; idx += 256){
        int hh = idx >> 5, r = idx & 31;
        int h = h0 + hh;
        float fr = (h < HN / 2) ? (float)h : (float)(h - HN);
        float sv, cv; sincosf(-CC * ((float)r - off0) * fr, &sv, &cv);
        rkT[hh][r] = make_float2(cv, sv);
    }
    __syncthreads();
    cplx a0[4], a1[4];
    #pragma unroll
    for (int u = 0; u < 4; ++u){ a0[u] = make_float2(0.f,0.f); a1[u] = make_float2(0.f,0.f); }
    const cplx* pc = P + ((size_t)b * HN + h0) * WN + w;

    float4 pvA[4], pvB[4];
    #pragma unroll
    for (int k = 0; k < 4; ++k) pvA[k] = *(const float4*)(pc + (size_t)k * WN);

    #pragma unroll 1
    for (int hh = 0; hh < HCH; hh += 8){
        #pragma unroll
        for (int k = 0; k < 4; ++k)
            pvB[k] = *(const float4*)(pc + (size_t)(hh + 4 + k) * WN);
        #pragma unroll
        for (int k = 0; k < 4; ++k){
            float4 rk01 = *(const float4*)&rkT[hh + k][rbase * 4];
            float4 rk23 = *(const float4*)&rkT[hh + k][rbase * 4 + 2];
            float wvx[4] = {rk01.x, rk01.z, rk23.x, rk23.z};
            float wvy[4] = {rk01.y, rk01.w, rk23.y, rk23.w};
            #pragma unroll
            for (int u = 0; u < 4; ++u){
                a0[u].x += wvx[u] * pvA[k].x + wvy[u] * pvA[k].y;
                a0[u].y += wvy[u] * pvA[k].x - wvx[u] * pvA[k].y;
                a1[u].x += wvx[u] * pvA[k].z + wvy[u] * pvA[k].w;
                a1[u].y += wvy[u] * pvA[k].z - wvx[u] * pvA[k].w;
            }
        }
        if (hh + 8 < HCH){
            #pragma unroll
            for (int k = 0; k < 4; ++k)
                pvA[k] = *(const float4*)(pc + (size_t)(hh + 8 + k) * WN);
        }
        #pragma unroll
        for (int k = 0; k < 4; ++k){
            float4 rk01 = *(const float4*)&rkT[hh + 4 + k][rbase * 4];
            float4 rk23 = *(const float4*)&rkT[hh + 4 + k][rbase * 4 + 2];
            float wvx[4] = {rk01.x, rk01.z, rk23.x, rk23.z};
            float wvy[4] = {rk01.y, rk01.w, rk23.y, rk23.w};
            #pragma unroll
            for (int u = 0; u < 4; ++u){
                a0[u].x += wvx[u] * pvB[k].x + wvy[u] * pvB[k].y;
                a0[u].y += wvy[u] * pvB[k].x - wvx[u] * pvB[k].y;
                a1[u].x += wvx[u] * pvB[k].z + wvy[u] * pvB[k].w;
                a1[u].y += wvy[u] * pvB[k].z - wvx[u] * pvB[k].w;
            }
        }
    }

    #pragma unroll
    for (int u = 0; u < 4; ++u){
        int r = rbase * 4 + u;
        if (r < REGION){
            float4* dst = (float4*)(Tpart + (((size_t)hs * BN + b) * REGION + r) * WN + w);
            *dst = make_float4(a0[u].x, a0[u].y, a1[u].x, a1[u].y);
        }
    }
}

// Dedicated w=256 column of Tpart (per-hs partials, same h-ascending order).
// grid (BN), block 256; threads 0..239 active: r = tid>>3, hs = tid&7.
__global__ void upsample_T256(const cplx* __restrict__ P, const float* __restrict__ small,
                              cplx* __restrict__ Tpart){
    const int b = blockIdx.x;
    const int tid = threadIdx.x;
    if (tid >= REGION * HS) return;
    const int r  = tid >> 3;
    const int hs = tid & 7;
    const int h0 = hs * HCH;
    const float off0 = small[b * 4 + 2];
    const float CC = TWO_PI / (HN * UFV);
    const float rr = (float)r - off0;
    const cplx* pc = P + ((size_t)b * HN + h0) * WN + 256;
    cplx acc = make_float2(0.f, 0.f);
    for (int hh = 0; hh < HCH; ++hh){
        int h = h0 + hh;
        float fr = (h < HN / 2) ? (float)h : (float)(h - HN);
        float sv, cv; sincosf(-CC * rr * fr, &sv, &cv);
        cplx p = pc[(size_t)hh * WN];
        acc.x += cv * p.x + sv * p.y;      // rk * conj(p)
        acc.y += sv * p.x - cv * p.y;
    }
    Tpart[(((size_t)hs * BN + b) * REGION + r) * WN + 256] = acc;
}

// Partial U with Hermitian fold, 32-wide chunks:
// U[r][c] = T[0]ck0 + T[256]ck256 + sum_{w=1}^{255} 2*Re(T[w]ck[w][c]) + kappa_r*S2(c),
// kappa_r = 2i*sin(CC*(r-off0)*256), S2 = sum_{w=1}^{255} P[256][w]*conj(ck[w][c]).
// grid (WS=8, BN), block 256; chunk ws covers w in [ws*32, ws*32+31]; ws==0 adds specials.
__global__ void upsample_U_part(const cplx* __restrict__ Tpart, const cplx* __restrict__ P,
                                const float* __restrict__ small, cplx* __restrict__ Upart){
    const int ws = blockIdx.x, b = blockIdx.y;
    const int tid = threadIdx.x;
    const int w0 = ws * WCH;
    const float off0 = small[b * 4 + 2];
    const float off1 = small[b * 4 + 3];
    const float CW = TWO_PI / (WN * UFV);
    const float CH = TWO_PI / (HN * UFV);
    __shared__ float2 Ts[REGION][WCH];
    __shared__ float2 ck[WCH][REGION];
    __shared__ float2 p256[WCH];
    __shared__ float2 T256s[REGION];
    const size_t TS = (size_t)BN * REGION * WN;
    for (int idx = tid; idx < REGION * WCH; idx += 256){
        int r = idx >> 5, ww = idx & (WCH - 1);
        cplx s = make_float2(0.f, 0.f);
        #pragma unroll
        for (int hs = 0; hs < HS; ++hs)
            s = cadd(s, Tpart[(size_t)hs * TS + ((size_t)b * REGION + r) * WN + w0 + ww]);
        Ts[r][ww] = s;
    }
    if (tid < WCH) p256[tid] = P[((size_t)b * HN + 256) * WN + w0 + tid];
    if (ws == 0 && tid >= 64 && tid < 64 + REGION){
        int r = tid - 64;
        cplx s = make_float2(0.f, 0.f);
        #pragma unroll
        for (int hs = 0; hs < HS; ++hs)
            s = cadd(s, Tpart[(size_t)hs * TS + ((size_t)b * REGION + r) * WN + 256]);
        T256s[r] = s;
    }
    for (int idx = tid; idx < WCH * REGION; idx += 256){
        int ww = idx / REGION, c = idx - ww * REGION;
        int w = w0 + ww;                       // 0..255 -> fw = w
        float sv, cv; sincosf(-CW * (float)w * ((float)c - off1), &sv, &cv);
        ck[ww][c] = make_float2(cv, sv);
    }
    __syncthreads();
    const int start = (ws == 0) ? 1 : 0;       // skip w=0 in the folded sum
    #pragma unroll
    for (int q = 0; q < 4; ++q){
        int o = tid + 256 * q;
        if (o < REGION * REGION){
            int r = o / REGION, c = o - r * REGION;
            float racc = 0.f;
            cplx s2 = make_float2(0.f, 0.f);
            for (int ww = start; ww < WCH; ++ww){
                float2 T = Ts[r][ww], K = ck[ww][c];
                racc += T.x * K.x - T.y * K.y;         // Re(T*K)
                float2 pv = p256[ww];
                s2.x += pv.x * K.x + pv.y * K.y;       // S2 += p256*conj(K)
                s2.y += pv.y * K.x - pv.x * K.y;
            }
            float th = CH * ((float)r - off0) * 256.0f;
            float snt = sinf(th);
            cplx contrib = make_float2(2.f * racc - 2.f * snt * s2.y,
                                       2.f * snt * s2.x);
            if (ws == 0){
                contrib = cadd(contrib, Ts[r][0]);     // w=0 term (ck=1)
                float s256, c256; sincosf(CW * 256.0f * ((float)c - off1), &s256, &c256);
                contrib = cadd(contrib, cmul(T256s[r], make_float2(c256, s256)));  // w=256
            }
            Upart[((size_t)ws * BN + b) * (REGION * REGION) + o] = contrib;
        }
    }
}

// Sum the WS U-partials, argmax |U|^2, final shifts. grid (BN), block 256.
__global__ void upsample_argmax(const cplx* __restrict__ Upart, const float* __restrict__ small,
                                float* __restrict__ out){
    const int b = blockIdx.x;
    const int tid = threadIdx.x;
    float best = -1.0f; int bidx = 0x7fffffff;
    #pragma unroll
    for (int q = 0; q < 4; ++q){
        int o = tid + 256 * q;
        if (o < REGION * REGION){
            cplx u = make_float2(0.f, 0.f);
            #pragma unroll
            for (int ws = 0; ws < WS; ++ws)
                u = cadd(u, Upart[((size_t)ws * BN + b) * (REGION * REGION) + o]);
            float m = u.x * u.x + u.y * u.y;
            if (m > best){ best = m; bidx = o; }
        }
    }
    __shared__ float vals[256];
    __shared__ int   idxs[256];
    vals[tid] = best; idxs[tid] = bidx;
    __syncthreads();
    for (int s = 128; s > 0; s >>= 1){
        if (tid < s){
            if (vals[tid + s] > vals[tid] ||
                (vals[tid + s] == vals[tid] && idxs[tid + s] < idxs[tid])){
                vals[tid] = vals[tid + s]; idxs[tid] = idxs[tid + s];
            }
        }
        __syncthreads();
    }
    if (tid == 0){
        int o = idxs[0];
        float r = (float)(o / REGION) - DFTSHIFT;
        float c = (float)(o % REGION) - DFTSHIFT;
        out[b * 2 + 0] = small[b * 4 + 0] + r / UFV;
        out[b * 2 + 1] = small[b * 4 + 1] + c / UFV;
    }
}

extern "C" void kernel_launch(void* const* d_in, const int* in_sizes, int n_in,
                              void* d_out, int out_size, void* d_ws, size_t ws_size,
                              hipStream_t stream){
    const float* tgt = (const float*)d_in[0];
    const float* src = (const float*)d_in[1];
    float* out = (float*)d_out;

    const size_t BIG = (size_t)BN * HN * WN;      // 8,388,608 complex = 67 MB
    cplx* buf1 = (cplx*)d_ws;                     // F_z -> P (image_product)
    cplx* buf2 = buf1 + BIG;                      // cc rows -> Tpart / Upart
    float* small = (float*)(buf2 + BIG);
    float2* cand = (float2*)(small + 128);

    const size_t TSTRIDE = (size_t)BN * REGION * WN;   // 3.93 MB
    cplx* Tpart = buf2;                                // HS(8) * TSTRIDE = 31.5 MB
    cplx* Upart = buf2 + HS * TSTRIDE;                 // WS*BN*900 tiny

    dim3 blk(256);
    row_fft_pack<<<dim3(BN * HN / 4), blk, 0, stream>>>(tgt, src, buf1);
    col_fft_fwd<<<dim3(WN / 8, BN), dim3(512), 0, stream>>>(buf1);
    cross_rowinv<<<dim3((257 + 3) / 4, BN), blk, 0, stream>>>(buf1, buf2);
    colinv_argmax<<<dim3(WN / 8, BN), dim3(512), 0, stream>>>(buf2, cand);
    coarse_reduce<<<dim3(BN), dim3(64), 0, stream>>>(cand, small);
    upsample_T<<<dim3(4, BN, HS), blk, 0, stream>>>(buf1, small, Tpart);
    upsample_T256<<<dim3(BN), blk, 0, stream>>>(buf1, small, Tpart);
    upsample_U_part<<<dim3(WS, BN), blk, 0, stream>>>(Tpart, buf1, small, Upart);
    upsample_argmax<<<dim3(BN), blk, 0, stream>>>(Upart, small, out);
}

// Round 23
// 168.952 us; speedup vs baseline: 1.1116x; 1.1116x over previous
//
#include <hip/hip_runtime.h>
#include <math.h>

#define BN 32
#define HN 512
#define WN 512
#define REGION 30
#define RPAD 32
#define UFV 20.0f
#define DFTSHIFT 15.0f
#define TWO_PI 6.2831853071795864769f
#define HS 8              // h-chunks for upsample_T partials
#define HCH (HN / HS)     // 64
#define WS 8              // w-chunks for upsample_U partials (32 w each)
#define WCH 32

typedef float2 cplx;

__device__ __forceinline__ cplx cmul(cplx a, cplx b){
    return make_float2(a.x*b.x - a.y*b.y, a.x*b.y + a.y*b.x);
}
__device__ __forceinline__ cplx cadd(cplx a, cplx b){
    return make_float2(a.x + b.x, a.y + b.y);
}
__device__ __forceinline__ cplx csub(cplx a, cplx b){
    return make_float2(a.x - b.x, a.y - b.y);
}
__device__ __forceinline__ int brev9(int i){ return (int)(__brev((unsigned)i) >> 23); }
__device__ __forceinline__ int brev6(int i){ return (int)(__brev((unsigned)i) >> 26); }
// col-FFT LDS layout: stride 546 (== 2 mod 16) + h>>4 skew -> ~4 lanes/bank-pair
__device__ __forceinline__ int csl(int h, int c){ return c * 546 + h + (h >> 4); }

#define BFLY(a,b,w){ cplx t_ = cmul(w,b); b = make_float2(a.x - t_.x, a.y - t_.y); a = cadd(a, t_); }
#define BFLY1(a,b){ cplx t_ = b; b = make_float2(a.x - t_.x, a.y - t_.y); a = cadd(a, t_); }

// ---- wave-level 512-pt FFT: 64 lanes, 8 elems/lane in registers, radix-2 DIT
// Input:  v[j] = x[brev9(8*lane+j)]   Output: v[j] = X[64*j + lane]
__device__ __forceinline__ void fft512_regs(cplx* v, const float2* tw, cplx* ds, int lane){
    const cplx wI  = *(const cplx*)&tw[128];   // (0, sign)
    const cplx w8a = *(const cplx*)&tw[64];
    const cplx w8b = *(const cplx*)&tw[192];
    BFLY1(v[0],v[1]); BFLY1(v[2],v[3]); BFLY1(v[4],v[5]); BFLY1(v[6],v[7]);
    BFLY1(v[0],v[2]); BFLY(v[1],v[3],wI); BFLY1(v[4],v[6]); BFLY(v[5],v[7],wI);
    BFLY1(v[0],v[4]); BFLY(v[1],v[5],w8a); BFLY(v[2],v[6],wI); BFLY(v[3],v[7],w8b);
    const int h = lane >> 3, lo = lane & 7;
    const int bw = 9 * lane;
    const int br = 72 * h + lo;
    #pragma unroll
    for (int j = 0; j < 8; ++j) ds[bw + j] = v[j];
    asm volatile("s_waitcnt lgkmcnt(0)" ::: "memory");
    #pragma unroll
    for (int j = 0; j < 8; ++j) v[j] = ds[br + 9*j];
    {
        cplx wA = *(const cplx*)&tw[lo<<5];
        BFLY(v[0],v[1],wA); BFLY(v[2],v[3],wA); BFLY(v[4],v[5],wA); BFLY(v[6],v[7],wA);
        cplx wB0 = *(const cplx*)&tw[lo<<4], wB1 = *(const cplx*)&tw[128+(lo<<4)];
        BFLY(v[0],v[2],wB0); BFLY(v[1],v[3],wB1); BFLY(v[4],v[6],wB0); BFLY(v[5],v[7],wB1);
        cplx wC0 = *(const cplx*)&tw[lo<<3], wC1 = *(const cplx*)&tw[64+(lo<<3)];
        cplx wC2 = *(const cplx*)&tw[128+(lo<<3)], wC3 = *(const cplx*)&tw[192+(lo<<3)];
        BFLY(v[0],v[4],wC0); BFLY(v[1],v[5],wC1); BFLY(v[2],v[6],wC2); BFLY(v[3],v[7],wC3);
    }
    #pragma unroll
    for (int j = 0; j < 8; ++j) ds[br + 9*j] = v[j];
    asm volatile("s_waitcnt lgkmcnt(0)" ::: "memory");
    const int br3 = lane + (lane >> 3);
    #pragma unroll
    for (int j = 0; j < 8; ++j) v[j] = ds[br3 + 72*j];
    {
        cplx wD = *(const cplx*)&tw[lane<<2];
        BFLY(v[0],v[1],wD); BFLY(v[2],v[3],wD); BFLY(v[4],v[5],wD); BFLY(v[6],v[7],wD);
        cplx wE0 = *(const cplx*)&tw[lane<<1], wE1 = *(const cplx*)&tw[128+(lane<<1)];
        BFLY(v[0],v[2],wE0); BFLY(v[1],v[3],wE1); BFLY(v[4],v[6],wE0); BFLY(v[5],v[7],wE1);
        cplx wF0 = *(const cplx*)&tw[lane], wF1 = *(const cplx*)&tw[64+lane];
        cplx wF2 = *(const cplx*)&tw[128+lane], wF3 = *(const cplx*)&tw[192+lane];
        BFLY(v[0],v[4],wF0); BFLY(v[1],v[5],wF1); BFLY(v[2],v[6],wF2); BFLY(v[3],v[7],wF3);
    }
}

// Packed row FFT: F_z rows of z = tgt + i*src. Wave-per-row. grid (BN*HN/4), block 256.
__global__ void __launch_bounds__(256) row_fft_pack(const float* __restrict__ tgt,
                                                    const float* __restrict__ src,
                                                    cplx* __restrict__ Fz){
    __shared__ float2 tw[256];
    __shared__ cplx ds[4 * 576];
    const int tid = threadIdx.x;
    { float sv, cv; sincosf(-TWO_PI * (float)tid * (1.0f/512.0f), &sv, &cv);
      tw[tid] = make_float2(cv, sv); }
    __syncthreads();
    const int wave = tid >> 6, lane = tid & 63;
    const int rid = blockIdx.x * 4 + wave;
    const float* tr = tgt + (size_t)rid * WN;
    const float* sr = src + (size_t)rid * WN;
    const int rb6 = brev6(lane);
    const int B3[8] = {0,256,128,384,64,320,192,448};      // brev3(j)*64
    cplx v[8];
    #pragma unroll
    for (int j = 0; j < 8; ++j){ int o = B3[j] + rb6; v[j] = make_float2(tr[o], sr[o]); }
    fft512_regs(v, (const float2*)tw, ds + wave * 576, lane);
    cplx* orow = Fz + (size_t)rid * WN;
    #pragma unroll
    for (int j = 0; j < 8; ++j) orow[64*j + lane] = v[j];
}

// ---- radix-8 column FFT, 8 cols/block, 512 threads: one radix-8 group per
// thread per pass, data staged BIT-REVERSED so pass 0 is in-place.
__device__ __forceinline__ void col_fft8_t512(cplx* sm, const float2* tw, int tid){
    const cplx wI  = tw[128];
    const cplx w8a = tw[64];
    const cplx w8b = tw[192];
    const int c = tid & 7;
    const int k = tid >> 3;                 // 0..63
    {
        cplx y[8];
        #pragma unroll
        for (int m = 0; m < 8; ++m) y[m] = sm[csl(8*k + m, c)];
        BFLY1(y[0],y[1]); BFLY1(y[2],y[3]); BFLY1(y[4],y[5]); BFLY1(y[6],y[7]);
        BFLY1(y[0],y[2]); BFLY(y[1],y[3],wI); BFLY1(y[4],y[6]); BFLY(y[5],y[7],wI);
        BFLY1(y[0],y[4]); BFLY(y[1],y[5],w8a); BFLY(y[2],y[6],wI); BFLY(y[3],y[7],w8b);
        #pragma unroll
        for (int m = 0; m < 8; ++m) sm[csl(8*k + m, c)] = y[m];
    }
    __syncthreads();
    #pragma unroll
    for (int pass = 1; pass < 3; ++pass){
        const int st = 3*pass + 1;          // 4, 7
        const int h1 = 1 << (st - 1);       // 8, 64
        const int q = k & (h1 - 1);
        const int i0 = ((k >> (st - 1)) << (st + 2)) + q;
        cplx x[8];
        #pragma unroll
        for (int m = 0; m < 8; ++m) x[m] = sm[csl(i0 + m*h1, c)];
        cplx w1 = tw[q << (9 - st)];
        BFLY(x[0],x[1],w1); BFLY(x[2],x[3],w1); BFLY(x[4],x[5],w1); BFLY(x[6],x[7],w1);
        cplx w2a = tw[q << (8 - st)];
        cplx w2b = tw[(q << (8 - st)) + 128];
        BFLY(x[0],x[2],w2a); BFLY(x[1],x[3],w2b); BFLY(x[4],x[6],w2a); BFLY(x[5],x[7],w2b);
        cplx w30 = tw[q << (7 - st)];
        cplx w31 = tw[(q << (7 - st)) + 64];
        cplx w32 = tw[(q << (7 - st)) + 128];
        cplx w33 = tw[(q << (7 - st)) + 192];
        BFLY(x[0],x[4],w30); BFLY(x[1],x[5],w31); BFLY(x[2],x[6],w32); BFLY(x[3],x[7],w33);
        #pragma unroll
        for (int m = 0; m < 8; ++m) sm[csl(i0 + m*h1, c)] = x[m];
        __syncthreads();
    }
}

// Column-wise forward FFT of F_z, 8 cols/block, 512 threads, in place. grid (WN/8, BN).
__global__ void __launch_bounds__(512) col_fft_fwd(cplx* __restrict__ buf){
    const int b  = blockIdx.y;
    const int w0 = blockIdx.x * 8;
    const int tid = threadIdx.x;
    __shared__ cplx sm[4368];
    __shared__ float2 tw[256];
    if (tid < 256){ float sv, cv; sincosf(-TWO_PI * (float)tid * (1.0f/512.0f), &sv, &cv);
      tw[tid] = make_float2(cv, sv); }
    cplx* base = buf + (size_t)b * HN * WN + w0;
    for (int idx = tid; idx < HN * 4; idx += 512){
        int h = idx >> 2, c2 = (idx & 3) << 1;
        float4 v = *(const float4*)(base + (size_t)h * WN + c2);
        int hb = brev9(h);
        sm[csl(hb, c2)]     = make_float2(v.x, v.y);
        sm[csl(hb, c2 + 1)] = make_float2(v.z, v.w);
    }
    __syncthreads();
    col_fft8_t512(sm, (const float2*)tw, tid);
    for (int idx = tid; idx < HN * 4; idx += 512){
        int h = idx >> 2, c2 = (idx & 3) << 1;
        cplx a = sm[csl(h, c2)], d = sm[csl(h, c2 + 1)];
        *(float4*)(base + (size_t)h * WN + c2) = make_float4(a.x, a.y, d.x, d.y);
    }
}

// Hermitian unpack + cross-power + row-wise inverse FFT. Wave-per-row-pair.
// Mirror cc rows NOT written (colinv reconstructs, bit-exact). P written only
// for w < 320 (downstream reads are all w<=256). grid (65, BN), block 256.
__global__ void __launch_bounds__(256) cross_rowinv(cplx* __restrict__ Fz, cplx* __restrict__ cc){
    __shared__ float2 tw[256];
    __shared__ cplx ds[4 * 1184];
    const int tid = threadIdx.x;
    { float sv, cv; sincosf(TWO_PI * (float)tid * (1.0f/512.0f), &sv, &cv);
      tw[tid] = make_float2(cv, sv); }
    __syncthreads();
    const int wave = tid >> 6, lane = tid & 63;
    const int p = blockIdx.x * 4 + wave;
    if (p > 256) return;
    const int b = blockIdx.y;
    const int h1 = p, h2 = (HN - p) & (HN - 1);
    cplx* r1 = Fz + ((size_t)b * HN + h1) * WN;
    cplx* r2 = Fz + ((size_t)b * HN + h2) * WN;
    cplx* A = ds + wave * 1184;
    cplx* B = A + 592;
    #pragma unroll
    for (int u = 0; u < 8; ++u){
        A[lane + 64*u] = r1[lane + 64*u];
        B[lane + 64*u] = r2[lane + 64*u];
    }
    asm volatile("s_waitcnt lgkmcnt(0)" ::: "memory");
    const int rb6 = brev6(lane);
    const int B3[8] = {0,256,128,384,64,320,192,448};
    cplx v1[8];
    #pragma unroll
    for (int j = 0; j < 8; ++j){
        int w  = B3[j] + rb6;
        int wm = (WN - w) & (WN - 1);
        cplx Aw = A[w], Bw = B[w], Am = A[wm], Bm = B[wm];
        // P(k) = -i*(X - conj(Y))*conj(X + conj(Y))/4
        { cplx Bc = make_float2(Bm.x, -Bm.y);
          cplx s = cadd(Aw, Bc);
          cplx d = make_float2(Aw.x - Bc.x, Aw.y - Bc.y);
          cplx D = make_float2(d.x*s.x + d.y*s.y, d.y*s.x - d.x*s.y);
          v1[j] = make_float2(0.25f * D.y, -0.25f * D.x); }
        if (w < 320){
          cplx Ac = make_float2(Am.x, -Am.y);
          cplx s = cadd(Bw, Ac);
          cplx d = make_float2(Bw.x - Ac.x, Bw.y - Ac.y);
          cplx D = make_float2(d.x*s.x + d.y*s.y, d.y*s.x - d.x*s.y);
          r2[w] = make_float2(0.25f * D.y, -0.25f * D.x);     // P row h2 writeback
          r1[w] = v1[j];                                      // P row h1 writeback
        }
    }
    fft512_regs(v1, (const float2*)tw, A, lane);
    cplx* c1 = cc + ((size_t)b * HN + h1) * WN;
    #pragma unroll
    for (int j = 0; j < 8; ++j) c1[64*j + lane] = v1[j];
    // mirror rows 257..511 intentionally not written (reconstructed in colinv)
}

// Column-wise inverse FFT + per-block argmax of |cc|^2. 512 threads. grid (WN/8, BN).
__global__ void __launch_bounds__(512) colinv_argmax(const cplx* __restrict__ buf,
                                                     float2* __restrict__ cand){
    const int b  = blockIdx.y;
    const int w0 = blockIdx.x * 8;
    const int tid = threadIdx.x;
    __shared__ cplx sm[4368];
    __shared__ float2 tw[256];
    __shared__ float wv_[8];
    __shared__ int   wi_[8];
    if (tid < 256){ float sv, cv; sincosf(TWO_PI * (float)tid * (1.0f/512.0f), &sv, &cv);
      tw[tid] = make_float2(cv, sv); }
    const cplx* base = buf + (size_t)b * HN * WN + w0;
    for (int idx = tid; idx < 257 * 4; idx += 512){
        int h = idx >> 2, c2 = (idx & 3) << 1;
        float4 v = *(const float4*)(base + (size_t)h * WN + c2);
        int hb = brev9(h);
        sm[csl(hb, c2)]     = make_float2(v.x, v.y);
        sm[csl(hb, c2 + 1)] = make_float2(v.z, v.w);
    }
    __syncthreads();
    for (int idx = tid; idx < 255 * 8; idx += 512){
        int h = 257 + (idx >> 3), c = idx & 7;
        cplx v = sm[csl(brev9(HN - h), c)];
        sm[csl(brev9(h), c)] = make_float2(v.x, -v.y);
    }
    __syncthreads();
    col_fft8_t512(sm, (const float2*)tw, tid);
    float best = -1.0f; int bidx = 0x7fffffff;
    for (int idx = tid; idx < HN * 8; idx += 512){
        int h = idx >> 3, c = idx & 7;
        cplx v = sm[csl(h, c)];
        float mm = v.x * v.x + v.y * v.y;
        if (mm > best){ best = mm; bidx = h * WN + w0 + c; }
    }
    for (int off = 32; off > 0; off >>= 1){
        float v2 = __shfl_down(best, off);
        int   i2 = __shfl_down(bidx, off);
        if (v2 > best || (v2 == best && i2 < bidx)){ best = v2; bidx = i2; }
    }
    if ((tid & 63) == 0){ wv_[tid >> 6] = best; wi_[tid >> 6] = bidx; }
    __syncthreads();
    if (tid == 0){
        float bv = wv_[0]; int bx = wi_[0];
        #pragma unroll
        for (int w2 = 1; w2 < 8; ++w2){
            if (wv_[w2] > bv || (wv_[w2] == bv && wi_[w2] < bx)){ bv = wv_[w2]; bx = wi_[w2]; }
        }
        cand[b * 64 + blockIdx.x] = make_float2(bv, __int_as_float(bx));
    }
}

// Reduce 64 candidates per batch -> coarse shifts + upsample offsets. grid BN, block 64.
__global__ void coarse_reduce(const float2* __restrict__ cand, float* __restrict__ small){
    const int b = blockIdx.x, t = threadIdx.x;
    float2 c = cand[b * 64 + t];
    float v = c.x; int ix = __float_as_int(c.y);
    for (int off = 32; off > 0; off >>= 1){
        float v2 = __shfl_down(v, off);
        int   i2 = __shfl_down(ix, off);
        if (v2 > v || (v2 == v && i2 < ix)){ v = v2; ix = i2; }
    }
    if (t == 0){
        int row = ix / WN, col = ix % WN;
        float sr = (row > HN / 2) ? (float)(row - HN) : (float)row;
        float sc = (col > WN / 2) ? (float)(col - WN) : (float)col;
        small[b * 4 + 0] = sr;
        small[b * 4 + 1] = sc;
        small[b * 4 + 2] = DFTSHIFT - sr * UFV;
        small[b * 4 + 3] = DFTSHIFT - sc * UFV;
    }
}

// Partial T for w = 0..319 (w>256 unused, but tile 4 supplies w=256).
// grid (5, BN, HS=8), block 256 = 8 r-groups x 32 w-pairs.
// rk table TRANSPOSED [HCH][RPAD]: per-row reads are 2 x b128 (contiguous r).
__global__ void __launch_bounds__(256, 3) upsample_T(const cplx* __restrict__ P,
                                                     const float* __restrict__ small,
                                                     cplx* __restrict__ Tpart){
    const int b = blockIdx.y, hs = blockIdx.z;
    const int tid = threadIdx.x;
    const int wp = tid & 31;
    const int rbase = tid >> 5;
    const int w = blockIdx.x * 64 + wp * 2;
    const int h0 = hs * HCH;
    const float off0 = small[b * 4 + 2];
    const float CC = TWO_PI / (HN * UFV);
    __shared__ float2 rkT[HCH][RPAD];     // 16 KB, transposed
    for (int idx = tid; idx < HCH * RPAD; idx += 256){
        int hh = idx >> 5, r = idx & 31;
        int h = h0 + hh;
        float fr = (h < HN / 2) ? (float)h : (float)(h - HN);
        float sv, cv; sincosf(-CC * ((float)r - off0) * fr, &sv, &cv);
        rkT[hh][r] = make_float2(cv, sv);
    }
    __syncthreads();
    cplx a0[4], a1[4];
    #pragma unroll
    for (int u = 0; u < 4; ++u){ a0[u] = make_float2(0.f,0.f); a1[u] = make_float2(0.f,0.f); }
    const cplx* pc = P + ((size_t)b * HN + h0) * WN + w;

    float4 pvA[4], pvB[4];
    #pragma unroll
    for (int k = 0; k < 4; ++k) pvA[k] = *(const float4*)(pc + (size_t)k * WN);

    #pragma unroll 1
    for (int hh = 0; hh < HCH; hh += 8){
        #pragma unroll
        for (int k = 0; k < 4; ++k)
            pvB[k] = *(const float4*)(pc + (size_t)(hh + 4 + k) * WN);
        #pragma unroll
        for (int k = 0; k < 4; ++k){
            float4 rk01 = *(const float4*)&rkT[hh + k][rbase * 4];
            float4 rk23 = *(const float4*)&rkT[hh + k][rbase * 4 + 2];
            float wvx[4] = {rk01.x, rk01.z, rk23.x, rk23.z};
            float wvy[4] = {rk01.y, rk01.w, rk23.y, rk23.w};
            #pragma unroll
            for (int u = 0; u < 4; ++u){
                a0[u].x += wvx[u] * pvA[k].x + wvy[u] * pvA[k].y;
                a0[u].y += wvy[u] * pvA[k].x - wvx[u] * pvA[k].y;
                a1[u].x += wvx[u] * pvA[k].z + wvy[u] * pvA[k].w;
                a1[u].y += wvy[u] * pvA[k].z - wvx[u] * pvA[k].w;
            }
        }
        if (hh + 8 < HCH){
            #pragma unroll
            for (int k = 0; k < 4; ++k)
                pvA[k] = *(const float4*)(pc + (size_t)(hh + 8 + k) * WN);
        }
        #pragma unroll
        for (int k = 0; k < 4; ++k){
            float4 rk01 = *(const float4*)&rkT[hh + 4 + k][rbase * 4];
            float4 rk23 = *(const float4*)&rkT[hh + 4 + k][rbase * 4 + 2];
            float wvx[4] = {rk01.x, rk01.z, rk23.x, rk23.z};
            float wvy[4] = {rk01.y, rk01.w, rk23.y, rk23.w};
            #pragma unroll
            for (int u = 0; u < 4; ++u){
                a0[u].x += wvx[u] * pvB[k].x + wvy[u] * pvB[k].y;
                a0[u].y += wvy[u] * pvB[k].x - wvx[u] * pvB[k].y;
                a1[u].x += wvx[u] * pvB[k].z + wvy[u] * pvB[k].w;
                a1[u].y += wvy[u] * pvB[k].z - wvx[u] * pvB[k].w;
            }
        }
    }

    #pragma unroll
    for (int u = 0; u < 4; ++u){
        int r = rbase * 4 + u;
        if (r < REGION){
            float4* dst = (float4*)(Tpart + (((size_t)hs * BN + b) * REGION + r) * WN + w);
            *dst = make_float4(a0[u].x, a0[u].y, a1[u].x, a1[u].y);
        }
    }
}

// Partial U with Hermitian fold, 32-wide chunks:
// U[r][c] = T[0]ck0 + T[256]ck256 + sum_{w=1}^{255} 2*Re(T[w]ck[w][c]) + kappa_r*S2(c),
// kappa_r = 2i*sin(CC*(r-off0)*256), S2 = sum_{w=1}^{255} P[256][w]*conj(ck[w][c]).
// grid (WS=8, BN), block 256; chunk ws covers w in [ws*32, ws*32+31]; ws==0 adds specials.
__global__ void upsample_U_part(const cplx* __restrict__ Tpart, const cplx* __restrict__ P,
                                const float* __restrict__ small, cplx* __restrict__ Upart){
    const int ws = blockIdx.x, b = blockIdx.y;
    const int tid = threadIdx.x;
    const int w0 = ws * WCH;
    const float off0 = small[b * 4 + 2];
    const float off1 = small[b * 4 + 3];
    const float CW = TWO_PI / (WN * UFV);
    const float CH = TWO_PI / (HN * UFV);
    __shared__ float2 Ts[REGION][WCH];
    __shared__ float2 ck[WCH][REGION];
    __shared__ float2 p256[WCH];
    __shared__ float2 T256s[REGION];
    const size_t TS = (size_t)BN * REGION * WN;
    for (int idx = tid; idx < REGION * WCH; idx += 256){
        int r = idx >> 5, ww = idx & (WCH - 1);
        cplx s = make_float2(0.f, 0.f);
        #pragma unroll
        for (int hs = 0; hs < HS; ++hs)
            s = cadd(s, Tpart[(size_t)hs * TS + ((size_t)b * REGION + r) * WN + w0 + ww]);
        Ts[r][ww] = s;
    }
    if (tid < WCH) p256[tid] = P[((size_t)b * HN + 256) * WN + w0 + tid];
    if (ws == 0 && tid >= 64 && tid < 64 + REGION){
        int r = tid - 64;
        cplx s = make_float2(0.f, 0.f);
        #pragma unroll
        for (int hs = 0; hs < HS; ++hs)
            s = cadd(s, Tpart[(size_t)hs * TS + ((size_t)b * REGION + r) * WN + 256]);
        T256s[r] = s;
    }
    for (int idx = tid; idx < WCH * REGION; idx += 256){
        int ww = idx / REGION, c = idx - ww * REGION;
        int w = w0 + ww;                       // 0..255 -> fw = w
        float sv, cv; sincosf(-CW * (float)w * ((float)c - off1), &sv, &cv);
        ck[ww][c] = make_float2(cv, sv);
    }
    __syncthreads();
    const int start = (ws == 0) ? 1 : 0;       // skip w=0 in the folded sum
    #pragma unroll
    for (int q = 0; q < 4; ++q){
        int o = tid + 256 * q;
        if (o < REGION * REGION){
            int r = o / REGION, c = o - r * REGION;
            float racc = 0.f;
            cplx s2 = make_float2(0.f, 0.f);
            for (int ww = start; ww < WCH; ++ww){
                float2 T = Ts[r][ww], K = ck[ww][c];
                racc += T.x * K.x - T.y * K.y;         // Re(T*K)
                float2 pv = p256[ww];
                s2.x += pv.x * K.x + pv.y * K.y;       // S2 += p256*conj(K)
                s2.y += pv.y * K.x - pv.x * K.y;
            }
            float th = CH * ((float)r - off0) * 256.0f;
            float snt = sinf(th);
            cplx contrib = make_float2(2.f * racc - 2.f * snt * s2.y,
                                       2.f * snt * s2.x);
            if (ws == 0){
                contrib = cadd(contrib, Ts[r][0]);     // w=0 term (ck=1)
                float s256, c256; sincosf(CW * 256.0f * ((float)c - off1), &s256, &c256);
                contrib = cadd(contrib, cmul(T256s[r], make_float2(c256, s256)));  // w=256
            }
            Upart[((size_t)ws * BN + b) * (REGION * REGION) + o] = contrib;
        }
    }
}

// Sum the WS U-partials, argmax |U|^2, final shifts. grid (BN), block 256.
__global__ void upsample_argmax(const cplx* __restrict__ Upart, const float* __restrict__ small,
                                float* __restrict__ out){
    const int b = blockIdx.x;
    const int tid = threadIdx.x;
    float best = -1.0f; int bidx = 0x7fffffff;
    #pragma unroll
    for (int q = 0; q < 4; ++q){
        int o = tid + 256 * q;
        if (o < REGION * REGION){
            cplx u = make_float2(0.f, 0.f);
            #pragma unroll
            for (int ws = 0; ws < WS; ++ws)
                u = cadd(u, Upart[((size_t)ws * BN + b) * (REGION * REGION) + o]);
            float m = u.x * u.x + u.y * u.y;
            if (m > best){ best = m; bidx = o; }
        }
    }
    __shared__ float vals[256];
    __shared__ int   idxs[256];
    vals[tid] = best; idxs[tid] = bidx;
    __syncthreads();
    for (int s = 128; s > 0; s >>= 1){
        if (tid < s){
            if (vals[tid + s] > vals[tid] ||
                (vals[tid + s] == vals[tid] && idxs[tid + s] < idxs[tid])){
                vals[tid] = vals[tid + s]; idxs[tid] = idxs[tid + s];
            }
        }
        __syncthreads();
    }
    if (tid == 0){
        int o = idxs[0];
        float r = (float)(o / REGION) - DFTSHIFT;
        float c = (float)(o % REGION) - DFTSHIFT;
        out[b * 2 + 0] = small[b * 4 + 0] + r / UFV;
        out[b * 2 + 1] = small[b * 4 + 1] + c / UFV;
    }
}

extern "C" void kernel_launch(void* const* d_in, const int* in_sizes, int n_in,
                              void* d_out, int out_size, void* d_ws, size_t ws_size,
                              hipStream_t stream){
    const float* tgt = (const float*)d_in[0];
    const float* src = (const float*)d_in[1];
    float* out = (float*)d_out;

    const size_t BIG = (size_t)BN * HN * WN;      // 8,388,608 complex = 67 MB
    cplx* buf1 = (cplx*)d_ws;                     // F_z -> P (image_product)
    cplx* buf2 = buf1 + BIG;                      // cc rows -> Tpart / Upart
    float* small = (float*)(buf2 + BIG);
    float2* cand = (float2*)(small + 128);

    const size_t TSTRIDE = (size_t)BN * REGION * WN;   // 3.93 MB
    cplx* Tpart = buf2;                                // HS(8) * TSTRIDE = 31.5 MB
    cplx* Upart = buf2 + HS * TSTRIDE;                 // WS*BN*900 tiny

    dim3 blk(256);
    row_fft_pack<<<dim3(BN * HN / 4), blk, 0, stream>>>(tgt, src, buf1);
    col_fft_fwd<<<dim3(WN / 8, BN), dim3(512), 0, stream>>>(buf1);
    cross_rowinv<<<dim3((257 + 3) / 4, BN), blk, 0, stream>>>(buf1, buf2);
    colinv_argmax<<<dim3(WN / 8, BN), dim3(512), 0, stream>>>(buf2, cand);
    coarse_reduce<<<dim3(BN), dim3(64), 0, stream>>>(cand, small);
    upsample_T<<<dim3(5, BN, HS), blk, 0, stream>>>(buf1, small, Tpart);
    upsample_U_part<<<dim3(WS, BN), blk, 0, stream>>>(Tpart, buf1, small, Upart);
    upsample_argmax<<<dim3(BN), blk, 0, stream>>>(Upart, small, out);
}